// Round 1
// baseline (257.449 us; speedup 1.0000x reference)
//
#include <hip/hip_runtime.h>
#include <hip/hip_fp16.h>

typedef _Float16 half8 __attribute__((ext_vector_type(8)));
typedef float f32x4 __attribute__((ext_vector_type(4)));

static constexpr int SS = 2048, DD = 512;
static constexpr int MM = 2 * SS;   // 4096 rows (b,s)
static constexpr int PAD = 72;      // LDS row pitch in f16 (144B = 9*16B, 16B-aligned rows)

// ---------------- kernel 1: x + positional encoding -> fp16 ----------------
__global__ __launch_bounds__(256) void pe_kernel(const float* __restrict__ x,
                                                 _Float16* __restrict__ xb) {
    int idx = blockIdx.x * 256 + threadIdx.x;
    if (idx >= MM * DD) return;
    int d = idx & (DD - 1);
    int s = (idx >> 9) & (SS - 1);
    int dd = d & 255;
    // 10000^(-dd/256) = exp(-dd * ln(10000)/256)
    float p = __expf(-(float)dd * 0.03597789207803197f);
    float ang = (float)s * p;
    float pe = (d < 256) ? sinf(ang) : cosf(ang);
    xb[idx] = (_Float16)(x[idx] + pe);
}

// ---------------- kernel 2: transpose+cast weights -> WbT[n][k] fp16 --------
__global__ __launch_bounds__(256) void wt_kernel(const float* __restrict__ Wq,
                                                 const float* __restrict__ Wk,
                                                 const float* __restrict__ Wv,
                                                 _Float16* __restrict__ WbT) {
    __shared__ float tile[64][65];
    int tk = blockIdx.x;   // 0..7   k-block
    int tn = blockIdx.y;   // 0..23  n-block
    const float* W = (tn < 8) ? Wq : (tn < 16) ? Wk : Wv;
    int nbase = (tn & 7) * 64;
    int t = threadIdx.x;
    for (int i = 0; i < 16; ++i) {
        int e = t + i * 256;
        int row = e >> 6, col = e & 63;            // row=k, col=n
        tile[row][col] = W[(tk * 64 + row) * 512 + nbase + col];
    }
    __syncthreads();
    for (int i = 0; i < 16; ++i) {
        int e = t + i * 256;
        int row = e >> 6, col = e & 63;            // row=n, col=k
        WbT[(size_t)(tn * 64 + row) * 512 + tk * 64 + col] = (_Float16)tile[col][row];
    }
}

// ---------------- kernel 3: QKV GEMM (M=4096, N=1536, K=512) ----------------
// C = xb @ W + bias.  Epilogue scatters q / per-scale-gathered K / transposed V.
__global__ __launch_bounds__(256) void qkv_gemm(
    const _Float16* __restrict__ xb, const _Float16* __restrict__ WbT,
    const float* __restrict__ bq, const float* __restrict__ bk, const float* __restrict__ bv,
    _Float16* __restrict__ qbuf,
    _Float16* __restrict__ k1, _Float16* __restrict__ k2, _Float16* __restrict__ k4,
    _Float16* __restrict__ v1, _Float16* __restrict__ v2, _Float16* __restrict__ v4)
{
    __shared__ _Float16 As[128][PAD];
    __shared__ _Float16 Bs[128][PAD];
    int bm = blockIdx.x, bn = blockIdx.y;
    int t = threadIdx.x;
    int w = t >> 6, lane = t & 63;
    int wm = w >> 1, wn = w & 1;
    int l15 = lane & 15, lg = lane >> 4;

    f32x4 zero = {0.f, 0.f, 0.f, 0.f};
    f32x4 acc[4][4];
    for (int i = 0; i < 4; ++i)
        for (int j = 0; j < 4; ++j) acc[i][j] = zero;

    for (int kt = 0; kt < 8; ++kt) {
        for (int i = 0; i < 4; ++i) {
            int e = t + i * 256;                   // 0..1023
            int row = e >> 3, c8 = (e & 7) * 8;
            *(half8*)&As[row][c8] =
                *(const half8*)&xb[(size_t)(bm * 128 + row) * 512 + kt * 64 + c8];
            *(half8*)&Bs[row][c8] =
                *(const half8*)&WbT[(size_t)(bn * 128 + row) * 512 + kt * 64 + c8];
        }
        __syncthreads();
        for (int kk = 0; kk < 2; ++kk) {
            half8 af[4], bf[4];
            for (int mi = 0; mi < 4; ++mi)
                af[mi] = *(const half8*)&As[wm * 64 + mi * 16 + l15][kk * 32 + lg * 8];
            for (int ni = 0; ni < 4; ++ni)
                bf[ni] = *(const half8*)&Bs[wn * 64 + ni * 16 + l15][kk * 32 + lg * 8];
            for (int mi = 0; mi < 4; ++mi)
                for (int ni = 0; ni < 4; ++ni)
                    acc[mi][ni] = __builtin_amdgcn_mfma_f32_16x16x32_f16(
                        af[mi], bf[ni], acc[mi][ni], 0, 0, 0);
        }
        __syncthreads();
    }

    int colbase = bn * 128 + wn * 64;
    int rowbase = bm * 128 + wm * 64;
    for (int ni = 0; ni < 4; ++ni) {
        int n = colbase + ni * 16 + l15;
        float bias = (n < 512) ? bq[n] : (n < 1024) ? bk[n - 512] : bv[n - 1024];
        for (int mi = 0; mi < 4; ++mi) {
            for (int r = 0; r < 4; ++r) {
                int m = rowbase + mi * 16 + lg * 4 + r;
                float val = acc[mi][ni][r] + bias;
                _Float16 hv = (_Float16)val;
                int b = m >> 11, s = m & 2047;
                if (n < 512) {
                    qbuf[(size_t)m * 512 + n] = hv;
                } else if (n < 1024) {
                    int nk = n - 512, h = nk >> 6, hd = nk & 63, bh = b * 8 + h;
                    k1[((size_t)bh * 2048 + s) * 64 + hd] = hv;
                    if ((s & 1) == 0) k2[((size_t)bh * 1024 + (s >> 1)) * 64 + hd] = hv;
                    if ((s & 3) == 0) k4[((size_t)bh * 512 + (s >> 2)) * 64 + hd] = hv;
                } else {
                    int nv = n - 1024, h = nv >> 6, hd = nv & 63, bh = b * 8 + h;
                    v1[((size_t)bh * 64 + hd) * 2048 + s] = hv;
                    if ((s & 1) == 0) v2[((size_t)bh * 64 + hd) * 1024 + (s >> 1)] = hv;
                    if ((s & 3) == 0) v4[((size_t)bh * 64 + hd) * 512 + (s >> 2)] = hv;
                }
            }
        }
    }
}

// ---------------- kernel 4: multi-scale flash attention ----------------
// grid (32 qblocks, 16 bh); 4 waves x 16 q-rows; loops 3 scales, writes mean/3.
__global__ __launch_bounds__(256) void attn_kernel(
    const _Float16* __restrict__ qbuf,
    const _Float16* __restrict__ k1, const _Float16* __restrict__ k2, const _Float16* __restrict__ k4,
    const _Float16* __restrict__ v1, const _Float16* __restrict__ v2, const _Float16* __restrict__ v4,
    float* __restrict__ out)
{
    __shared__ _Float16 pl[4][16][PAD];
    int qb = blockIdx.x;     // 0..31
    int bh = blockIdx.y;     // 0..15
    int b = bh >> 3, h = bh & 7;
    int t = threadIdx.x, w = t >> 6, lane = t & 63;
    int l15 = lane & 15, lg = lane >> 4;
    int qrow0 = qb * 64 + w * 16;

    half8 qf[2];
    for (int kk = 0; kk < 2; ++kk)
        qf[kk] = *(const half8*)&qbuf[((size_t)(b * 2048 + qrow0 + l15)) * 512
                                      + h * 64 + kk * 32 + lg * 8];

    const _Float16* kptr[3] = {k1, k2, k4};
    const _Float16* vptr[3] = {v1, v2, v4};

    f32x4 zero = {0.f, 0.f, 0.f, 0.f};
    f32x4 osum[4];
    for (int i = 0; i < 4; ++i) osum[i] = zero;

#pragma unroll
    for (int si = 0; si < 3; ++si) {
        const int Sk = 2048 >> si;
        const _Float16* kp = kptr[si] + (size_t)bh * Sk * 64;
        const _Float16* vp = vptr[si] + (size_t)bh * 64 * Sk;

        float m_run[4], l_run[4];
        f32x4 oacc[4];
        for (int r = 0; r < 4; ++r) { m_run[r] = -1e30f; l_run[r] = 0.f; }
        for (int i = 0; i < 4; ++i) oacc[i] = zero;

        for (int kb = 0; kb < (Sk >> 6); ++kb) {
            // ---- QK^T : scores[16q][64k] for this wave's 16 q rows
            f32x4 sacc[4];
            for (int c = 0; c < 4; ++c) sacc[c] = zero;
            for (int c = 0; c < 4; ++c) {
                half8 kf0 = *(const half8*)&kp[(size_t)(kb * 64 + c * 16 + l15) * 64 + lg * 8];
                half8 kf1 = *(const half8*)&kp[(size_t)(kb * 64 + c * 16 + l15) * 64 + 32 + lg * 8];
                sacc[c] = __builtin_amdgcn_mfma_f32_16x16x32_f16(qf[0], kf0, sacc[c], 0, 0, 0);
                sacc[c] = __builtin_amdgcn_mfma_f32_16x16x32_f16(qf[1], kf1, sacc[c], 0, 0, 0);
            }
            for (int c = 0; c < 4; ++c)
                for (int r = 0; r < 4; ++r) sacc[c][r] *= 0.125f;

            // ---- online softmax (row r of group lg; reduce over 16 lanes)
            float fac[4];
            for (int r = 0; r < 4; ++r) {
                float v = fmaxf(fmaxf(sacc[0][r], sacc[1][r]), fmaxf(sacc[2][r], sacc[3][r]));
                v = fmaxf(v, __shfl_xor(v, 1));
                v = fmaxf(v, __shfl_xor(v, 2));
                v = fmaxf(v, __shfl_xor(v, 4));
                v = fmaxf(v, __shfl_xor(v, 8));
                float mnew = fmaxf(m_run[r], v);
                fac[r] = __expf(m_run[r] - mnew);
                m_run[r] = mnew;
            }
            float psum[4] = {0.f, 0.f, 0.f, 0.f};
            for (int c = 0; c < 4; ++c)
                for (int r = 0; r < 4; ++r) {
                    float p = __expf(sacc[c][r] - m_run[r]);
                    sacc[c][r] = p;
                    psum[r] += p;
                }
            for (int r = 0; r < 4; ++r) {
                float v = psum[r];
                v += __shfl_xor(v, 1);
                v += __shfl_xor(v, 2);
                v += __shfl_xor(v, 4);
                v += __shfl_xor(v, 8);
                l_run[r] = l_run[r] * fac[r] + v;
            }
            for (int hc = 0; hc < 4; ++hc)
                for (int r = 0; r < 4; ++r) oacc[hc][r] *= fac[r];

            // ---- P: D-layout -> A-operand layout via LDS (wave-private tile)
            for (int c = 0; c < 4; ++c)
                for (int r = 0; r < 4; ++r)
                    pl[w][lg * 4 + r][c * 16 + l15] = (_Float16)sacc[c][r];
            half8 pf0 = *(const half8*)&pl[w][l15][lg * 8];
            half8 pf1 = *(const half8*)&pl[w][l15][32 + lg * 8];

            // ---- PV : out[16q][64hd] += P[16][64] * V[64][64]
            for (int hc = 0; hc < 4; ++hc) {
                half8 vf0 = *(const half8*)&vp[(size_t)(hc * 16 + l15) * Sk + kb * 64 + lg * 8];
                half8 vf1 = *(const half8*)&vp[(size_t)(hc * 16 + l15) * Sk + kb * 64 + 32 + lg * 8];
                oacc[hc] = __builtin_amdgcn_mfma_f32_16x16x32_f16(pf0, vf0, oacc[hc], 0, 0, 0);
                oacc[hc] = __builtin_amdgcn_mfma_f32_16x16x32_f16(pf1, vf1, oacc[hc], 0, 0, 0);
            }
        }
        for (int hc = 0; hc < 4; ++hc)
            for (int r = 0; r < 4; ++r)
                osum[hc][r] += oacc[hc][r] / l_run[r];
    }

    const float third = 1.0f / 3.0f;
    for (int hc = 0; hc < 4; ++hc)
        for (int r = 0; r < 4; ++r) {
            int s = qrow0 + lg * 4 + r;
            out[((size_t)(b * 2048 + s)) * 512 + h * 64 + hc * 16 + l15] = osum[hc][r] * third;
        }
}

// ---------------- launch ----------------
extern "C" void kernel_launch(void* const* d_in, const int* in_sizes, int n_in,
                              void* d_out, int out_size, void* d_ws, size_t ws_size,
                              hipStream_t stream) {
    const float* x  = (const float*)d_in[0];
    const float* Wq = (const float*)d_in[1];
    const float* bq = (const float*)d_in[2];
    const float* Wk = (const float*)d_in[3];
    const float* bk = (const float*)d_in[4];
    const float* Wv = (const float*)d_in[5];
    const float* bv = (const float*)d_in[6];
    float* out = (float*)d_out;

    char* ws = (char*)d_ws;
    _Float16* xb   = (_Float16*)ws; ws += (size_t)4096 * 512 * 2;
    _Float16* WbT  = (_Float16*)ws; ws += (size_t)1536 * 512 * 2;
    _Float16* qbuf = (_Float16*)ws; ws += (size_t)4096 * 512 * 2;
    _Float16* k1   = (_Float16*)ws; ws += (size_t)16 * 2048 * 64 * 2;
    _Float16* k2   = (_Float16*)ws; ws += (size_t)16 * 1024 * 64 * 2;
    _Float16* k4   = (_Float16*)ws; ws += (size_t)16 * 512 * 64 * 2;
    _Float16* v1   = (_Float16*)ws; ws += (size_t)16 * 2048 * 64 * 2;
    _Float16* v2   = (_Float16*)ws; ws += (size_t)16 * 1024 * 64 * 2;
    _Float16* v4   = (_Float16*)ws; ws += (size_t)16 * 512 * 64 * 2;

    hipLaunchKernelGGL(pe_kernel, dim3(8192), dim3(256), 0, stream, x, xb);
    hipLaunchKernelGGL(wt_kernel, dim3(8, 24), dim3(256), 0, stream, Wq, Wk, Wv, WbT);
    hipLaunchKernelGGL(qkv_gemm, dim3(32, 12), dim3(256), 0, stream,
                       xb, WbT, bq, bk, bv, qbuf, k1, k2, k4, v1, v2, v4);
    hipLaunchKernelGGL(attn_kernel, dim3(32, 16), dim3(256), 0, stream,
                       qbuf, k1, k2, k4, v1, v2, v4, out);
}